// Round 7
// baseline (1077.799 us; speedup 1.0000x reference)
//
#include <hip/hip_runtime.h>
#include <stdint.h>

#define N_NODES 50000
#define N_EDGES 800000
#define HIDDEN  64
#define EDGE_F  32
#define CAT     160   // 2H + F
#define CAT2    128   // 2H

typedef __attribute__((ext_vector_type(8))) short          bf16x8;
typedef __attribute__((ext_vector_type(4))) float          f32x4;
typedef __attribute__((ext_vector_type(4))) unsigned short u16x4;
typedef __attribute__((ext_vector_type(2))) unsigned int   u32x2;

// RNE fp32 -> bf16 (prep kernel only; hot path uses v_cvt_pk_bf16_f32)
static __device__ __forceinline__ unsigned short f2bf(float f) {
  unsigned int u = __builtin_bit_cast(unsigned int, f);
  return (unsigned short)((u + 0x7fffu + ((u >> 16) & 1u)) >> 16);
}

// packed fp32x2 -> bf16x2 (RNE), 1 instruction
static __device__ __forceinline__ unsigned int cvt_pk_bf16(float a, float b) {
  unsigned int r;
  asm("v_cvt_pk_bf16_f32 %0, %1, %2" : "=v"(r) : "v"(a), "v"(b));
  return r;
}

// ---------------- prep: zb = bf16(z); weights -> bf16 transposed; cnt=0 -------
// mode 0 (CSR): zero cnt. mode 1 (fallback): copy z -> znode (atomic target).
__global__ __launch_bounds__(256) void prep_kernel(
    const float* __restrict__ z, const float* __restrict__ Wffw,
    const float* __restrict__ Wf, const float* __restrict__ Ws,
    float* __restrict__ znode, unsigned short* __restrict__ zb,
    unsigned short* __restrict__ WtF,   // [160][160] (n-major, k-contig)
    unsigned short* __restrict__ Wfs,   // [128][128]; rows 0..63 = f, 64..127 = s
    int* __restrict__ cnt, int mode) {
  int i = blockIdx.x * 256 + threadIdx.x;
  if (i < N_NODES * HIDDEN / 4) {
    f32x4 v = ((const f32x4*)z)[i];
    if (mode == 1) ((f32x4*)znode)[i] = v;
    u16x4 o = { f2bf(v[0]), f2bf(v[1]), f2bf(v[2]), f2bf(v[3]) };
    ((u16x4*)zb)[i] = o;
  }
  if (i < CAT * CAT) {
    int n = i / CAT, k = i % CAT;
    WtF[i] = f2bf(Wffw[k * CAT + n]);
  }
  if (i < CAT2 * CAT2) {
    int n = i / CAT2, k = i % CAT2;
    float v = (n < HIDDEN) ? Wf[k * HIDDEN + n] : Ws[k * HIDDEN + (n - HIDDEN)];
    Wfs[i] = f2bf(v);
  }
  if (mode == 0 && i < N_NODES) cnt[i] = 0;
}

// ---------------- CSR build: histogram -> scan -> scatter ---------------------
__global__ __launch_bounds__(256) void hist_kernel(
    const int* __restrict__ ei, int* __restrict__ cnt) {
  int e = blockIdx.x * 256 + threadIdx.x;         // grid = 3125 exactly
  atomicAdd(&cnt[ei[N_EDGES + e]], 1);
}

// single-block exclusive scan of cnt[50000] -> offs, cursor (wave shfl scan)
__global__ __launch_bounds__(1024) void scan_kernel(
    const int* __restrict__ cnt, int* __restrict__ offs, int* __restrict__ cursor) {
  __shared__ int wsum[16];
  __shared__ int carry_s;
  const int tid  = threadIdx.x;
  const int lane = tid & 63;
  const int wid  = tid >> 6;
  if (tid == 0) carry_s = 0;
  __syncthreads();
  for (int base = 0; base < N_NODES; base += 1024) {
    int i = base + tid;
    int v = (i < N_NODES) ? cnt[i] : 0;
    int s = v;                                    // wave inclusive scan
    #pragma unroll
    for (int d = 1; d < 64; d <<= 1) {
      int t = __shfl_up(s, d);
      if (lane >= d) s += t;
    }
    if (lane == 63) wsum[wid] = s;
    __syncthreads();
    if (wid == 0) {
      int ws = (lane < 16) ? wsum[lane] : 0;
      #pragma unroll
      for (int d = 1; d < 16; d <<= 1) {
        int t = __shfl_up(ws, d);
        if (lane >= d) ws += t;
      }
      if (lane < 16) wsum[lane] = ws;             // inclusive wave-sum scan
    }
    __syncthreads();
    int wbase = (wid > 0) ? wsum[wid - 1] : 0;
    int excl  = carry_s + wbase + s - v;
    if (i < N_NODES) { offs[i] = excl; cursor[i] = excl; }
    __syncthreads();                              // reads of carry_s/wsum done
    if (tid == 0) carry_s += wsum[15];
    __syncthreads();
  }
  if (tid == 0) offs[N_NODES] = carry_s;          // = N_EDGES
}

__global__ __launch_bounds__(256) void scatter_kernel(
    const int* __restrict__ ei, int* __restrict__ cursor, int* __restrict__ eperm) {
  int e = blockIdx.x * 256 + threadIdx.x;         // grid = 3125 exactly
  int pos = atomicAdd(&cursor[ei[N_EDGES + e]], 1);
  eperm[pos] = e;
}

// ---------------- fused per-edge kernel: edge MLP GEMM + CGConv GEMM ----------
// MODE 0 (CSR): msg rows -> workspace, coalesced nontemporal (no atomics).
// MODE 1 (fallback, == R4 proven 386us): atomicAdd into znode.
// LDS 30720 B -> 5 blocks/CU: proven concurrency throttle (R2: 8 blk/CU
// thrashed L2/L3 FETCH 122->389 MB WRITE 794->1372 MB; R4 restored baseline).
//   Zs[64][128] bf16: 16B slots 0..7 = z_src, 8..15 = z_dst, XOR-swizzled
//     (physical slot p at row r holds logical slot (p&7)^(r&7) | (p&8)).
//     Staged by global_load_lds width=16 with lane-linear LDS dest; swizzle is
//     pre-applied to the per-lane GLOBAL chunk (m173 pattern).
//   Ea[64][32] bf16: edge_attr, 16B slots XOR-swizzled by (row&3).
#define ZS_LD 128
#define EA_LD 32
#define ZS_PAD 5120   // shorts; pads LDS block to 30720 B

template<int MODE>
__global__ __launch_bounds__(256, 5) void fused_edge_kernel(
    const unsigned short* __restrict__ zb, const float* __restrict__ ea,
    const int* __restrict__ ei,
    const unsigned short* __restrict__ WtF, const unsigned short* __restrict__ Wfs,
    const float* __restrict__ bffw, const float* __restrict__ bfv,
    const float* __restrict__ bsv,
    float* __restrict__ zedge, float* __restrict__ znode,
    float* __restrict__ msg) {
  __shared__ __align__(16) unsigned short Zs[64 * ZS_LD + ZS_PAD]; // 26624 B
  __shared__ __align__(16) unsigned short Ea[64 * EA_LD];          //  4096 B
  const int tid = threadIdx.x;
  const int eb  = blockIdx.x * 64;

  // stage z rows: 64 edges x 16 chunks of 16B, direct global->LDS DMA.
  #pragma unroll
  for (int i = 0; i < 4; ++i) {
    int tau  = tid + 256 * i;
    int el   = tau >> 4;
    int c    = tau & 15;
    int half = c >> 3;                 // 0 = src, 1 = dst
    int cc   = (c & 7) ^ (el & 7);     // pre-swizzled global chunk
    int node = ei[half * N_EDGES + eb + el];
    const unsigned short* src = &zb[node * HIDDEN + cc * 8];
    unsigned short* dst = &Zs[((tid & 0xC0) + i * 256) * 8]; // wave-uniform base
    __builtin_amdgcn_global_load_lds(
        (const __attribute__((address_space(1))) unsigned int*)src,
        (__attribute__((address_space(3))) unsigned int*)dst, 16, 0, 0);
  }
  // stage edge_attr (fp32->bf16 via cvt_pk), 16B-slot swizzled by (row&3)
  #pragma unroll
  for (int i = 0; i < 2; ++i) {
    int tau = tid + 256 * i;
    int el  = tau >> 3;
    int c   = tau & 7;
    f32x4 v = __builtin_nontemporal_load((const f32x4*)&ea[(eb + el) * EDGE_F + c * 4]);
    u32x2 o = { cvt_pk_bf16(v[0], v[1]), cvt_pk_bf16(v[2], v[3]) };
    int col = (c * 4) ^ ((el & 3) << 3);
    *(u32x2*)&Ea[el * EA_LD + col] = o;
  }
  __syncthreads();

  const int w    = tid >> 6;
  const int lane = tid & 63;
  const int ln   = lane & 15;
  const int q    = lane >> 4;
  const int mg   = w & 1;    // edge rows [mg*32, +32)
  const int nh   = w >> 1;   // edge-MLP col half [nh*80, +80); CG col half [nh*32, +32)
  const int xoZ  = (ln & 7) << 3;  // Zs read swizzle (shorts)
  const int xoE  = (ln & 3) << 3;  // Ea read swizzle (shorts)

  // ============ edge MLP: z_edge = relu(cat(src,dst,ea) @ Wffw + b) ============
  {
    f32x4 acc[5][2];
    #pragma unroll
    for (int t = 0; t < 5; ++t) {
      acc[t][0] = f32x4{0.f, 0.f, 0.f, 0.f};
      acc[t][1] = f32x4{0.f, 0.f, 0.f, 0.f};
    }
    #pragma unroll
    for (int ks = 0; ks < 5; ++ks) {
      bf16x8 a0, a1;
      if (ks < 4) {
        int off = (ks * 32 + q * 8) ^ xoZ;
        a0 = *(const bf16x8*)&Zs[(mg * 32 + ln) * ZS_LD + off];
        a1 = *(const bf16x8*)&Zs[(mg * 32 + 16 + ln) * ZS_LD + off];
      } else {
        int off = (q * 8) ^ xoE;
        a0 = *(const bf16x8*)&Ea[(mg * 32 + ln) * EA_LD + off];
        a1 = *(const bf16x8*)&Ea[(mg * 32 + 16 + ln) * EA_LD + off];
      }
      int k0 = ks * 32 + q * 8;
      #pragma unroll
      for (int t = 0; t < 5; ++t) {
        int n = nh * 80 + t * 16 + ln;
        bf16x8 b = *(const bf16x8*)&WtF[n * CAT + k0];
        acc[t][0] = __builtin_amdgcn_mfma_f32_16x16x32_bf16(a0, b, acc[t][0], 0, 0, 0);
        acc[t][1] = __builtin_amdgcn_mfma_f32_16x16x32_bf16(a1, b, acc[t][1], 0, 0, 0);
      }
    }
    #pragma unroll
    for (int t = 0; t < 5; ++t) {
      int n = nh * 80 + t * 16 + ln;
      float bias = bffw[n];
      #pragma unroll
      for (int ms = 0; ms < 2; ++ms) {
        #pragma unroll
        for (int r = 0; r < 4; ++r) {
          int m = mg * 32 + ms * 16 + q * 4 + r;
          float y = fmaxf(acc[t][ms][r] + bias, 0.0f);
          __builtin_nontemporal_store(y, &zedge[(eb + m) * CAT + n]);
        }
      }
    }
  }

  // ============ CGConv: msg = sig(cat(dst,src)@Wf+bf)*softplus(...Ws+bs) ======
  {
    f32x4 accF[2][2], accS[2][2];
    #pragma unroll
    for (int tt = 0; tt < 2; ++tt) {
      accF[tt][0] = f32x4{0.f, 0.f, 0.f, 0.f};
      accF[tt][1] = f32x4{0.f, 0.f, 0.f, 0.f};
      accS[tt][0] = f32x4{0.f, 0.f, 0.f, 0.f};
      accS[tt][1] = f32x4{0.f, 0.f, 0.f, 0.f};
    }
    // logical k = [dst(0..63) | src(64..127)]; physical Zs = [src | dst]
    const int cgoff[4] = {64, 96, 0, 32};
    #pragma unroll
    for (int ks = 0; ks < 4; ++ks) {
      int off = (cgoff[ks] + q * 8) ^ xoZ;
      bf16x8 a0 = *(const bf16x8*)&Zs[(mg * 32 + ln) * ZS_LD + off];
      bf16x8 a1 = *(const bf16x8*)&Zs[(mg * 32 + 16 + ln) * ZS_LD + off];
      int k0 = ks * 32 + q * 8;
      #pragma unroll
      for (int tt = 0; tt < 2; ++tt) {
        int n = nh * 32 + tt * 16 + ln;
        bf16x8 bF = *(const bf16x8*)&Wfs[n * CAT2 + k0];
        bf16x8 bS = *(const bf16x8*)&Wfs[(HIDDEN + n) * CAT2 + k0];
        accF[tt][0] = __builtin_amdgcn_mfma_f32_16x16x32_bf16(a0, bF, accF[tt][0], 0, 0, 0);
        accF[tt][1] = __builtin_amdgcn_mfma_f32_16x16x32_bf16(a1, bF, accF[tt][1], 0, 0, 0);
        accS[tt][0] = __builtin_amdgcn_mfma_f32_16x16x32_bf16(a0, bS, accS[tt][0], 0, 0, 0);
        accS[tt][1] = __builtin_amdgcn_mfma_f32_16x16x32_bf16(a1, bS, accS[tt][1], 0, 0, 0);
      }
    }
    int dc[2][4];
    if (MODE == 1) {
      #pragma unroll
      for (int ms = 0; ms < 2; ++ms)
        #pragma unroll
        for (int r = 0; r < 4; ++r)
          dc[ms][r] = ei[N_EDGES + eb + mg * 32 + ms * 16 + q * 4 + r];
    }

    #pragma unroll
    for (int tt = 0; tt < 2; ++tt) {
      int h = nh * 32 + tt * 16 + ln;
      float bf_ = bfv[h];
      float bs_ = bsv[h];
      #pragma unroll
      for (int ms = 0; ms < 2; ++ms) {
        #pragma unroll
        for (int r = 0; r < 4; ++r) {
          float xf  = accF[tt][ms][r] + bf_;
          float xs  = accS[tt][ms][r] + bs_;
          float sig = __builtin_amdgcn_rcpf(1.0f + __expf(-xf));
          float sp  = (xs > 20.0f) ? xs : __logf(1.0f + __expf(xs));
          float mval = sig * sp;
          if (MODE == 0) {
            int m = mg * 32 + ms * 16 + q * 4 + r;
            __builtin_nontemporal_store(mval, &msg[(size_t)(eb + m) * HIDDEN + h]);
          } else {
            atomicAdd(&znode[dc[ms][r] * HIDDEN + h], mval);
          }
        }
      }
    }
  }
}

// ---------------- aggregation: znode = z + segment_sum(msg) -------------------
// one wave per node; lane = feature. msg rows gathered via eperm (CSR order).
__global__ __launch_bounds__(256) void agg_kernel(
    const float* __restrict__ z, const float* __restrict__ msg,
    const int* __restrict__ eperm, const int* __restrict__ offs,
    float* __restrict__ znode) {
  const int lane = threadIdx.x & 63;
  const int node = blockIdx.x * 4 + (threadIdx.x >> 6);   // grid = 12500
  int beg = offs[node], end = offs[node + 1];
  float sum = 0.f;
  for (int b0 = beg; b0 < end; b0 += 64) {
    int rem = end - b0;
    int e_l = (lane < rem) ? eperm[b0 + lane] : 0;
    int c   = rem < 64 ? rem : 64;
    for (int j = 0; j < c; ++j) {
      int e = __shfl(e_l, j);
      sum += msg[(size_t)e * HIDDEN + lane];
    }
  }
  int idx = node * HIDDEN + lane;
  znode[idx] = z[idx] + sum;
}

extern "C" void kernel_launch(void* const* d_in, const int* in_sizes, int n_in,
                              void* d_out, int out_size, void* d_ws, size_t ws_size,
                              hipStream_t stream) {
  const float* z    = (const float*)d_in[0];
  const float* ea   = (const float*)d_in[1];
  const int*   ei   = (const int*)d_in[2];
  const float* Wffw = (const float*)d_in[3];
  const float* bffw = (const float*)d_in[4];
  const float* Wf   = (const float*)d_in[5];
  const float* bf_  = (const float*)d_in[6];
  const float* Ws   = (const float*)d_in[7];
  const float* bs_  = (const float*)d_in[8];

  float* znode = (float*)d_out;                       // [N_NODES, 64]
  float* zedge = znode + (size_t)N_NODES * HIDDEN;    // [N_EDGES, 160]

  // workspace layout
  unsigned short* zb  = (unsigned short*)d_ws;        // 6.4 MB
  unsigned short* WtF = zb + (size_t)N_NODES * HIDDEN;
  unsigned short* Wfs = WtF + CAT * CAT;
  float* msg   = (float*)(Wfs + CAT2 * CAT2);         // 204.8 MB
  int*   eperm = (int*)(msg + (size_t)N_EDGES * HIDDEN); // 3.2 MB
  int*   cnt    = eperm + N_EDGES;                    // 200 KB
  int*   offs   = cnt + N_NODES;                      // 200 KB (+1)
  int*   cursor = offs + N_NODES + 1;                 // 200 KB

  const size_t need = (size_t)((char*)(cursor + N_NODES) - (char*)d_ws);
  const bool csr = ws_size >= need;

  prep_kernel<<<(N_NODES * HIDDEN / 4 + 255) / 256, 256, 0, stream>>>(
      z, Wffw, Wf, Ws, znode, zb, WtF, Wfs, cnt, csr ? 0 : 1);

  if (csr) {
    hist_kernel<<<N_EDGES / 256, 256, 0, stream>>>(ei, cnt);
    scan_kernel<<<1, 1024, 0, stream>>>(cnt, offs, cursor);
    scatter_kernel<<<N_EDGES / 256, 256, 0, stream>>>(ei, cursor, eperm);
    fused_edge_kernel<0><<<N_EDGES / 64, 256, 0, stream>>>(
        zb, ea, ei, WtF, Wfs, bffw, bf_, bs_, zedge, znode, msg);
    agg_kernel<<<N_NODES / 4, 256, 0, stream>>>(z, msg, eperm, offs, znode);
  } else {
    fused_edge_kernel<1><<<N_EDGES / 64, 256, 0, stream>>>(
        zb, ea, ei, WtF, Wfs, bffw, bf_, bs_, zedge, znode, msg);
  }
}

// Round 8
// 835.358 us; speedup vs baseline: 1.2902x; 1.2902x over previous
//
#include <hip/hip_runtime.h>
#include <stdint.h>

#define N_NODES 50000
#define N_EDGES 800000
#define HIDDEN  64
#define EDGE_F  32
#define CAT     160   // 2H + F
#define CAT2    128   // 2H

typedef __attribute__((ext_vector_type(8))) short          bf16x8;
typedef __attribute__((ext_vector_type(4))) float          f32x4;
typedef __attribute__((ext_vector_type(4))) unsigned short u16x4;
typedef __attribute__((ext_vector_type(2))) unsigned int   u32x2;

// RNE fp32 -> bf16 (prep kernel only; hot path uses v_cvt_pk_bf16_f32)
static __device__ __forceinline__ unsigned short f2bf(float f) {
  unsigned int u = __builtin_bit_cast(unsigned int, f);
  return (unsigned short)((u + 0x7fffu + ((u >> 16) & 1u)) >> 16);
}

// packed fp32x2 -> bf16x2 (RNE), 1 instruction
static __device__ __forceinline__ unsigned int cvt_pk_bf16(float a, float b) {
  unsigned int r;
  asm("v_cvt_pk_bf16_f32 %0, %1, %2" : "=v"(r) : "v"(a), "v"(b));
  return r;
}

// ---------------- prep: znode = z; zb = bf16(z); weights -> bf16 transposed ----
__global__ __launch_bounds__(256) void prep_kernel(
    const float* __restrict__ z, const float* __restrict__ Wffw,
    const float* __restrict__ Wf, const float* __restrict__ Ws,
    float* __restrict__ znode, unsigned short* __restrict__ zb,
    unsigned short* __restrict__ WtF,   // [160][160] (n-major, k-contig)
    unsigned short* __restrict__ Wfs) { // [128][128]; rows 0..63 = f, 64..127 = s
  int i = blockIdx.x * 256 + threadIdx.x;
  if (i < N_NODES * HIDDEN / 4) {
    f32x4 v = ((const f32x4*)z)[i];
    ((f32x4*)znode)[i] = v;
    u16x4 o = { f2bf(v[0]), f2bf(v[1]), f2bf(v[2]), f2bf(v[3]) };
    ((u16x4*)zb)[i] = o;
  }
  if (i < CAT * CAT) {
    int n = i / CAT, k = i % CAT;
    WtF[i] = f2bf(Wffw[k * CAT + n]);
  }
  if (i < CAT2 * CAT2) {
    int n = i / CAT2, k = i % CAT2;
    float v = (n < HIDDEN) ? Wf[k * HIDDEN + n] : Ws[k * HIDDEN + (n - HIDDEN)];
    Wfs[i] = f2bf(v);
  }
}

// ---------------- fused per-edge kernel: 2 tiles/block, double-buffered -------
// R7 diagnosis: per-block lifetime ~90k cycles vs ~5k of work -> the serial
// chain [ei -> zb-gather DMA -> barrier -> compute -> store drain] is exposed
// once per tile. Fix: 2 tiles per block; tile-1's stage (z DMA + ea regs, T14
// split) is issued BEFORE tile-0's compute, hiding the gather latency.
// LDS 2*(16384+4096) = 40960 B -> exactly 4 blocks/CU: staging concurrency
// stays in the proven-safe regime (R2: 8 blk/CU thrashed L2/L3; R4: 5 ok).
//   Zs[64][128] bf16: 16B slots 0..7 = z_src, 8..15 = z_dst, XOR-swizzled
//     (physical slot p at row r holds logical slot (p&7)^(r&7) | (p&8)).
//     Staged by global_load_lds width=16 with lane-linear LDS dest; swizzle is
//     pre-applied to the per-lane GLOBAL chunk (m173 pattern).
//   Ea[64][32] bf16: edge_attr, 16B slots XOR-swizzled by (row&3).
#define ZS_LD 128
#define EA_LD 32

__global__ __launch_bounds__(256, 4) void fused_edge_kernel(
    const unsigned short* __restrict__ zb, const float* __restrict__ ea,
    const int* __restrict__ ei,
    const unsigned short* __restrict__ WtF, const unsigned short* __restrict__ Wfs,
    const float* __restrict__ bffw, const float* __restrict__ bfv,
    const float* __restrict__ bsv,
    float* __restrict__ zedge, float* __restrict__ znode) {
  __shared__ __align__(16) unsigned short Zs[2][64 * ZS_LD]; // 2 x 16384 B
  __shared__ __align__(16) unsigned short Ea[2][64 * EA_LD]; // 2 x  4096 B
  const int tid = threadIdx.x;
  const int eb0 = blockIdx.x * 128;

  const int w    = tid >> 6;
  const int lane = tid & 63;
  const int ln   = lane & 15;
  const int q    = lane >> 4;
  const int mg   = w & 1;    // edge rows [mg*32, +32)
  const int nh   = w >> 1;   // edge-MLP col half [nh*80, +80); CG col half [nh*32, +32)
  const int xoZ  = (ln & 7) << 3;  // Zs read swizzle (shorts)
  const int xoE  = (ln & 3) << 3;  // Ea read swizzle (shorts)

  // issue 16x16B-per-edge z gathers as global->LDS DMA (lane-linear dest)
  auto stage_z = [&](int buf, int eb) {
    #pragma unroll
    for (int i = 0; i < 4; ++i) {
      int tau  = tid + 256 * i;
      int el   = tau >> 4;
      int c    = tau & 15;
      int half = c >> 3;                 // 0 = src, 1 = dst
      int cc   = (c & 7) ^ (el & 7);     // pre-swizzled global chunk
      int node = ei[half * N_EDGES + eb + el];
      const unsigned short* src = &zb[node * HIDDEN + cc * 8];
      unsigned short* dst = &Zs[buf][((tid & 0xC0) + i * 256) * 8]; // wave-uniform base
      __builtin_amdgcn_global_load_lds(
          (const __attribute__((address_space(1))) unsigned int*)src,
          (__attribute__((address_space(3))) unsigned int*)dst, 16, 0, 0);
    }
  };
  auto load_ea = [&](int eb, f32x4* er) {   // T14: issue loads, hold in regs
    #pragma unroll
    for (int i = 0; i < 2; ++i) {
      int tau = tid + 256 * i;
      int el  = tau >> 3;
      int c   = tau & 7;
      er[i] = __builtin_nontemporal_load((const f32x4*)&ea[(eb + el) * EDGE_F + c * 4]);
    }
  };
  auto write_ea = [&](int buf, const f32x4* er) {  // cvt + swizzled LDS write
    #pragma unroll
    for (int i = 0; i < 2; ++i) {
      int tau = tid + 256 * i;
      int el  = tau >> 3;
      int c   = tau & 7;
      u32x2 o = { cvt_pk_bf16(er[i][0], er[i][1]), cvt_pk_bf16(er[i][2], er[i][3]) };
      int col = (c * 4) ^ ((el & 3) << 3);  // flips the 16B-slot bits only
      *(u32x2*)&Ea[buf][el * EA_LD + col] = o;
    }
  };

  auto compute = [&](int buf, int eb) {
    // ============ edge MLP: z_edge = relu(cat(src,dst,ea) @ Wffw + b) ==========
    {
      f32x4 acc[5][2];
      #pragma unroll
      for (int t = 0; t < 5; ++t) {
        acc[t][0] = f32x4{0.f, 0.f, 0.f, 0.f};
        acc[t][1] = f32x4{0.f, 0.f, 0.f, 0.f};
      }
      #pragma unroll
      for (int ks = 0; ks < 5; ++ks) {
        bf16x8 a0, a1;
        if (ks < 4) {
          int off = (ks * 32 + q * 8) ^ xoZ;
          a0 = *(const bf16x8*)&Zs[buf][(mg * 32 + ln) * ZS_LD + off];
          a1 = *(const bf16x8*)&Zs[buf][(mg * 32 + 16 + ln) * ZS_LD + off];
        } else {
          int off = (q * 8) ^ xoE;
          a0 = *(const bf16x8*)&Ea[buf][(mg * 32 + ln) * EA_LD + off];
          a1 = *(const bf16x8*)&Ea[buf][(mg * 32 + 16 + ln) * EA_LD + off];
        }
        int k0 = ks * 32 + q * 8;
        #pragma unroll
        for (int t = 0; t < 5; ++t) {
          int n = nh * 80 + t * 16 + ln;
          bf16x8 b = *(const bf16x8*)&WtF[n * CAT + k0];
          acc[t][0] = __builtin_amdgcn_mfma_f32_16x16x32_bf16(a0, b, acc[t][0], 0, 0, 0);
          acc[t][1] = __builtin_amdgcn_mfma_f32_16x16x32_bf16(a1, b, acc[t][1], 0, 0, 0);
        }
      }
      #pragma unroll
      for (int t = 0; t < 5; ++t) {
        int n = nh * 80 + t * 16 + ln;
        float bias = bffw[n];
        #pragma unroll
        for (int ms = 0; ms < 2; ++ms) {
          #pragma unroll
          for (int r = 0; r < 4; ++r) {
            int m = mg * 32 + ms * 16 + q * 4 + r;
            float y = fmaxf(acc[t][ms][r] + bias, 0.0f);
            __builtin_nontemporal_store(y, &zedge[(eb + m) * CAT + n]);
          }
        }
      }
    }
    // ============ CGConv: msg = sig(cat(dst,src)@Wf+bf)*softplus(...Ws+bs) ====
    {
      f32x4 accF[2][2], accS[2][2];
      #pragma unroll
      for (int tt = 0; tt < 2; ++tt) {
        accF[tt][0] = f32x4{0.f, 0.f, 0.f, 0.f};
        accF[tt][1] = f32x4{0.f, 0.f, 0.f, 0.f};
        accS[tt][0] = f32x4{0.f, 0.f, 0.f, 0.f};
        accS[tt][1] = f32x4{0.f, 0.f, 0.f, 0.f};
      }
      // logical k = [dst(0..63) | src(64..127)]; physical Zs = [src | dst]
      const int cgoff[4] = {64, 96, 0, 32};
      #pragma unroll
      for (int ks = 0; ks < 4; ++ks) {
        int off = (cgoff[ks] + q * 8) ^ xoZ;
        bf16x8 a0 = *(const bf16x8*)&Zs[buf][(mg * 32 + ln) * ZS_LD + off];
        bf16x8 a1 = *(const bf16x8*)&Zs[buf][(mg * 32 + 16 + ln) * ZS_LD + off];
        int k0 = ks * 32 + q * 8;
        #pragma unroll
        for (int tt = 0; tt < 2; ++tt) {
          int n = nh * 32 + tt * 16 + ln;
          bf16x8 bF = *(const bf16x8*)&Wfs[n * CAT2 + k0];
          bf16x8 bS = *(const bf16x8*)&Wfs[(HIDDEN + n) * CAT2 + k0];
          accF[tt][0] = __builtin_amdgcn_mfma_f32_16x16x32_bf16(a0, bF, accF[tt][0], 0, 0, 0);
          accF[tt][1] = __builtin_amdgcn_mfma_f32_16x16x32_bf16(a1, bF, accF[tt][1], 0, 0, 0);
          accS[tt][0] = __builtin_amdgcn_mfma_f32_16x16x32_bf16(a0, bS, accS[tt][0], 0, 0, 0);
          accS[tt][1] = __builtin_amdgcn_mfma_f32_16x16x32_bf16(a1, bS, accS[tt][1], 0, 0, 0);
        }
      }
      int dc[2][4];
      #pragma unroll
      for (int ms = 0; ms < 2; ++ms)
        #pragma unroll
        for (int r = 0; r < 4; ++r)
          dc[ms][r] = ei[N_EDGES + eb + mg * 32 + ms * 16 + q * 4 + r];

      #pragma unroll
      for (int tt = 0; tt < 2; ++tt) {
        int h = nh * 32 + tt * 16 + ln;
        float bf_ = bfv[h];
        float bs_ = bsv[h];
        #pragma unroll
        for (int ms = 0; ms < 2; ++ms) {
          #pragma unroll
          for (int r = 0; r < 4; ++r) {
            float xf  = accF[tt][ms][r] + bf_;
            float xs  = accS[tt][ms][r] + bs_;
            float sig = __builtin_amdgcn_rcpf(1.0f + __expf(-xf));  // v_exp + v_rcp
            float sp  = (xs > 20.0f) ? xs : __logf(1.0f + __expf(xs));
            atomicAdd(&znode[dc[ms][r] * HIDDEN + h], sig * sp);
          }
        }
      }
    }
  };

  // ---- prologue: stage tile 0 ----
  stage_z(0, eb0);
  {
    f32x4 er0[2];
    load_ea(eb0, er0);
    write_ea(0, er0);
  }
  __syncthreads();                       // drains tile-0 DMA + Ea[0] writes

  // ---- tile-1 prefetch (issued before tile-0 compute) ----
  f32x4 er1[2];
  load_ea(eb0 + 64, er1);                // held in regs across compute(0)
  stage_z(1, eb0 + 64);                  // DMA into buffer 1
  compute(0, eb0);                       // gather latency hides under this
  __syncthreads();                       // drains tile-1 DMA + tile-0 stores
  write_ea(1, er1);
  __syncthreads();                       // Ea[1] LDS visibility (cheap)
  compute(1, eb0 + 64);
}

extern "C" void kernel_launch(void* const* d_in, const int* in_sizes, int n_in,
                              void* d_out, int out_size, void* d_ws, size_t ws_size,
                              hipStream_t stream) {
  const float* z    = (const float*)d_in[0];
  const float* ea   = (const float*)d_in[1];
  const int*   ei   = (const int*)d_in[2];
  const float* Wffw = (const float*)d_in[3];
  const float* bffw = (const float*)d_in[4];
  const float* Wf   = (const float*)d_in[5];
  const float* bf_  = (const float*)d_in[6];
  const float* Ws   = (const float*)d_in[7];
  const float* bs_  = (const float*)d_in[8];

  float* znode = (float*)d_out;                       // [N_NODES, 64]
  float* zedge = znode + (size_t)N_NODES * HIDDEN;    // [N_EDGES, 160]

  unsigned short* zb  = (unsigned short*)d_ws;        // 50000*64 bf16 (6.4 MB)
  unsigned short* WtF = zb + (size_t)N_NODES * HIDDEN;
  unsigned short* Wfs = WtF + CAT * CAT;

  prep_kernel<<<(N_NODES * HIDDEN / 4 + 255) / 256, 256, 0, stream>>>(
      z, Wffw, Wf, Ws, znode, zb, WtF, Wfs);
  fused_edge_kernel<<<N_EDGES / 128, 256, 0, stream>>>(
      zb, ea, ei, WtF, Wfs, bffw, bf_, bs_, zedge, znode);
}